// Round 5
// baseline (216.487 us; speedup 1.0000x reference)
//
#include <hip/hip_runtime.h>

typedef unsigned short u16;
typedef unsigned int u32;
typedef float v4f __attribute__((ext_vector_type(4)));
typedef __bf16 bf16x8 __attribute__((ext_vector_type(8)));

// Problem constants: x (8, 768, 32x32), w_qkv (2304, 768), w_proj (768, 768)
#define BATCH 8
#define CDIM 768
#define NHEAD 12
#define DH 64
#define NSEQ 1024
// softmax scale folded with log2(e): logits * dh^-0.5 * log2e
#define SCL 0.18033688011112042f

__device__ __forceinline__ u16 f2bf(float f) {
  u32 u = __builtin_bit_cast(u32, f);
  u += 0x7fffu + ((u >> 16) & 1u);   // RNE
  return (u16)(u >> 16);
}

__device__ __forceinline__ v4f mfma16(bf16x8 a, bf16x8 b, v4f c) {
  return __builtin_amdgcn_mfma_f32_16x16x32_bf16(a, b, c, 0, 0, 0);
}

// async global->LDS DMA, 16B per lane; LDS dest = wave-uniform base + lane*16
__device__ __forceinline__ void gload16(const u16* g, u16* l) {
  __builtin_amdgcn_global_load_lds(
      (const __attribute__((address_space(1))) void*)g,
      (__attribute__((address_space(3))) void*)l, 16, 0, 0);
}

// ---------------- kernel: fp32 -> bf16 convert (weights) ----------------
__global__ __launch_bounds__(256) void k_conv(const float* __restrict__ s,
                                              u16* __restrict__ d, int n4) {
  int i = blockIdx.x * 256 + threadIdx.x;
  if (i < n4) {
    float4 v = ((const float4*)s)[i];
    u32 lo = (u32)f2bf(v.x) | ((u32)f2bf(v.y) << 16);
    u32 hi = (u32)f2bf(v.z) | ((u32)f2bf(v.w) << 16);
    ((uint2*)d)[i] = uint2{lo, hi};
  }
}

// ------------- kernel: x (b,c,p) fp32 -> xT (b,p,c) bf16 ----------------
__global__ __launch_bounds__(256) void k_transpose(const float* __restrict__ x,
                                                   u16* __restrict__ xT) {
  int b = blockIdx.z, c0 = blockIdx.y * 64, p0 = blockIdx.x * 64;
  __shared__ u16 Ts[64][72];   // pitch 72 keeps 16B alignment for b128 reads
  int t = threadIdx.x;
  int cr = t >> 4;             // 0..15
  int p4 = (t & 15) * 4;       // 0..60
  const float* src = x + ((size_t)b * CDIM + c0) * NSEQ + p0;
#pragma unroll
  for (int i = 0; i < 4; ++i) {
    int c = cr + i * 16;
    float4 v = *(const float4*)&src[(size_t)c * NSEQ + p4];
    Ts[p4 + 0][c] = f2bf(v.x);
    Ts[p4 + 1][c] = f2bf(v.y);
    Ts[p4 + 2][c] = f2bf(v.z);
    Ts[p4 + 3][c] = f2bf(v.w);
  }
  __syncthreads();
  int p = t >> 2;              // 0..63
  int cq = t & 3;
  u16* dst = xT + ((size_t)b * NSEQ + p0 + p) * CDIM + c0;
#pragma unroll
  for (int j = 0; j < 2; ++j) {
    int ch = cq + j * 4;       // 8 chunks of 8 bf16 = 64 elems
    *(int4*)&dst[ch * 8] = *(const int4*)&Ts[p][ch * 8];
  }
}

// ------------- kernel: QKV GEMM  D[o][p] = sum_c W[o][c] * xT[p][c] -----
// 256x128 tile, 512 threads / 8 waves, BK=32, unpadded LDS (pitch 64B),
// global_load_lds width=16 staging (3 DMA/wave/iter). Grid (oT,pT,b),
// oT-fastest (round-2 proven ordering; XCD affinity regressed — latency-
// bound kernel wants dispatch spread, not L2 pinning).
// Q,K rows (o<1536) stored transposed qkT[b][p][o]; V rows to vbuf[b][d][p].
__global__ __launch_bounds__(512) void k_gemm_qkv(const u16* __restrict__ Wb,
                                                  const u16* __restrict__ xT,
                                                  u16* __restrict__ qkT,
                                                  u16* __restrict__ vbuf) {
  int oT = blockIdx.x * 256, pT = blockIdx.y * 128, b = blockIdx.z;
  __shared__ u16 As[256 * 32];   // 16 KB
  __shared__ u16 Bs[128 * 32];   //  8 KB
  int t = threadIdx.x, lane = t & 63, wid = t >> 6;
  int ln = lane & 15, quad = lane >> 4;
  int wr = wid >> 1, wc = wid & 1;   // wave covers o rows wr*64.., p cols wc*64..
  v4f acc[4][4] = {};

  // DMA staging: A = 16 slabs of 16 rows (waves cover wid*16 and wid*16+128),
  // B = 8 slabs (wave wid -> rows wid*16). lane i -> row i/4, chunk (i%4)*8.
  int lr = lane >> 2, lc = (lane & 3) * 8;
  const u16* Ag = Wb + (size_t)(oT + wid * 16 + lr) * CDIM + lc;
  const u16* Bg = xT + ((size_t)b * NSEQ + pT + wid * 16 + lr) * CDIM + lc;
  u16* Asl = &As[(wid * 16) * 32];
  u16* Asl2 = &As[(wid * 16 + 128) * 32];
  u16* Bsl = &Bs[(wid * 16) * 32];

  for (int kk = 0; kk < CDIM; kk += 32) {
    gload16(Ag + kk, Asl);
    gload16(Ag + (size_t)128 * CDIM + kk, Asl2);
    gload16(Bg + kk, Bsl);
    __syncthreads();   // drains vmcnt (DMA) + barrier
    bf16x8 af[4], bfr[4];
#pragma unroll
    for (int mt = 0; mt < 4; ++mt)
      af[mt] = *(const bf16x8*)&As[(wr * 64 + mt * 16 + ln) * 32 + quad * 8];
#pragma unroll
    for (int nt = 0; nt < 4; ++nt)
      bfr[nt] = *(const bf16x8*)&Bs[(wc * 64 + nt * 16 + ln) * 32 + quad * 8];
#pragma unroll
    for (int mt = 0; mt < 4; ++mt)
#pragma unroll
      for (int nt = 0; nt < 4; ++nt)
        acc[mt][nt] = mfma16(af[mt], bfr[nt], acc[mt][nt]);
    __syncthreads();   // protect LDS from next iter's DMA
  }

  // oT tiles 0-5 are Q/K (o<1536), tiles 6-8 are V (clean 256-split)
  bool isV = (oT >= 2 * CDIM);
#pragma unroll
  for (int mt = 0; mt < 4; ++mt) {
#pragma unroll
    for (int nt = 0; nt < 4; ++nt) {
      int ro = oT + wr * 64 + mt * 16 + quad * 4;   // 4 consecutive o rows
      int cp = pT + wc * 64 + nt * 16 + ln;
      if (!isV) {
        u32 lo = (u32)f2bf(acc[mt][nt][0]) | ((u32)f2bf(acc[mt][nt][1]) << 16);
        u32 hi = (u32)f2bf(acc[mt][nt][2]) | ((u32)f2bf(acc[mt][nt][3]) << 16);
        *(uint2*)&qkT[((size_t)b * NSEQ + cp) * 1536 + ro] = uint2{lo, hi};
      } else {
#pragma unroll
        for (int r = 0; r < 4; ++r)
          vbuf[((size_t)b * CDIM + (ro - 2 * CDIM + r)) * NSEQ + cp] =
              f2bf(acc[mt][nt][r]);
      }
    }
  }
}

// ------------- kernel: flash attention (v3) -----------------------------
// 512 threads = 8 waves; block owns 256 query rows of one (b,h).
// 1-D grid decoded so flat_id%8 = b (XCD affinity): one batch's whole K+V
// (3.1 MB) stays in that XCD's L2; the 4 n-tile blocks per (b,h) are
// dispatch-adjacent so they stream K/V from L2, not HBM.
// S^T = K·Q^T (P exits in packed-per-lane m-order -> b64 LDS stores in
// A-layout); no-max softmax (logits N(0,~1.4) after scale), one final sum.
__global__ __launch_bounds__(512) void k_attn(const u16* __restrict__ qkT,
                                              const u16* __restrict__ vbuf,
                                              u16* __restrict__ attnT) {
  int id = blockIdx.x;
  int b = id & 7;              // XCD slot under flat%8 round-robin
  int j = id >> 3;
  int ntile = j & 3;
  int h = j >> 2;              // 0..11
  int nt0 = ntile * 256;

  int t = threadIdx.x, lane = t & 63, wid = t >> 6;
  int ln = lane & 15, quad = lane >> 4;
  int nbase = nt0 + wid * 32;

  __shared__ u16 Ks[64 * 72];      // [key m][dh k], pitch 72
  __shared__ u16 Vs[64 * 72];      // [d][key m], pitch 72
  __shared__ u16 Pa[8][32 * 72];   // per wave: [n_local][m_local], pitch 72
  u16* myP = Pa[wid];

  // Q frags (B operand of S^T): B[col=n][k], lane ln = n_local & 15
  const u16* qbase = qkT + ((size_t)b * NSEQ + nbase) * 1536 + h * DH;
  bf16x8 aq[2][2];
#pragma unroll
  for (int mt = 0; mt < 2; ++mt)
#pragma unroll
    for (int ks = 0; ks < 2; ++ks)
      aq[mt][ks] = *(const bf16x8*)&qbase[(size_t)(mt * 16 + ln) * 1536 + ks * 32 + quad * 8];

  v4f oacc[2][4] = {};
  float lsum[2] = {0.0f, 0.0f};

  const u16* kg0 = qkT + (size_t)b * NSEQ * 1536 + CDIM + h * DH;
  const u16* vg0 = vbuf + ((size_t)b * CDIM + h * DH) * NSEQ;
  int sr = t >> 3;              // 0..63 staging row (512 threads)
  int sc = (t & 7) * 8;         // 16B chunk within 64-elem row

  for (int m0 = 0; m0 < NSEQ; m0 += 64) {
    __syncthreads();            // all waves done reading prev Ks/Vs
    *(int4*)&Ks[sr * 72 + sc] = *(const int4*)(kg0 + (size_t)(m0 + sr) * 1536 + sc);
    *(int4*)&Vs[sr * 72 + sc] = *(const int4*)(vg0 + (size_t)sr * NSEQ + m0 + sc);
    __syncthreads();

    // S^T tiles: rows = keys (ct), cols = queries (mt); p = exp2(s*SCL)
#pragma unroll
    for (int ct = 0; ct < 4; ++ct) {
      bf16x8 kf0 = *(const bf16x8*)&Ks[(ct * 16 + ln) * 72 + quad * 8];
      bf16x8 kf1 = *(const bf16x8*)&Ks[(ct * 16 + ln) * 72 + 32 + quad * 8];
#pragma unroll
      for (int mt = 0; mt < 2; ++mt) {
        v4f s = {};
        s = mfma16(kf0, aq[mt][0], s);
        s = mfma16(kf1, aq[mt][1], s);
        float p0 = __builtin_amdgcn_exp2f(s[0] * SCL);
        float p1 = __builtin_amdgcn_exp2f(s[1] * SCL);
        float p2 = __builtin_amdgcn_exp2f(s[2] * SCL);
        float p3 = __builtin_amdgcn_exp2f(s[3] * SCL);
        lsum[mt] += (p0 + p1) + (p2 + p3);
        u32 lo = (u32)f2bf(p0) | ((u32)f2bf(p1) << 16);
        u32 hi = (u32)f2bf(p2) | ((u32)f2bf(p3) << 16);
        // lane holds P[n=mt*16+ln][m=ct*16+quad*4 .. +3] -> one 8B store
        *(uint2*)&myP[(mt * 16 + ln) * 72 + ct * 16 + quad * 4] = uint2{lo, hi};
      }
    }

    // PV: A = P (row=n, k=m), B = V (col=d, k=m)
    bf16x8 ap[2][2];
#pragma unroll
    for (int mt = 0; mt < 2; ++mt)
#pragma unroll
      for (int ks = 0; ks < 2; ++ks)
        ap[mt][ks] = *(const bf16x8*)&myP[(mt * 16 + ln) * 72 + ks * 32 + quad * 8];
#pragma unroll
    for (int nt = 0; nt < 4; ++nt) {
      bf16x8 vf0 = *(const bf16x8*)&Vs[(nt * 16 + ln) * 72 + quad * 8];
      bf16x8 vf1 = *(const bf16x8*)&Vs[(nt * 16 + ln) * 72 + 32 + quad * 8];
#pragma unroll
      for (int mt = 0; mt < 2; ++mt) {
        oacc[mt][nt] = mfma16(ap[mt][0], vf0, oacc[mt][nt]);
        oacc[mt][nt] = mfma16(ap[mt][1], vf1, oacc[mt][nt]);
      }
    }
  }

  // lsum[mt] per lane covers this quad's m-slices for n = mt*16+ln;
  // reduce across the 4 quad groups (lanes ln, ln+16, ln+32, ln+48).
#pragma unroll
  for (int mt = 0; mt < 2; ++mt) {
    lsum[mt] += __shfl_xor(lsum[mt], 16);
    lsum[mt] += __shfl_xor(lsum[mt], 32);
  }

  // normalize and store O as attnT[b][n][c]; O C-layout row = quad*4+r
#pragma unroll
  for (int mt = 0; mt < 2; ++mt) {
#pragma unroll
    for (int r = 0; r < 4; ++r) {
      float l = __shfl(lsum[mt], quad * 4 + r, 16);   // holder lane ln = quad*4+r
      float inv = 1.0f / l;
      int n = nbase + mt * 16 + quad * 4 + r;
      u16* dst = attnT + ((size_t)b * NSEQ + n) * CDIM + h * DH;
#pragma unroll
      for (int nt = 0; nt < 4; ++nt)
        dst[nt * 16 + ln] = f2bf(oacc[mt][nt][r] * inv);
    }
  }
}

// ------------- kernel: proj GEMM  out[o][p] = sum_c Wp[o][c]*attnT[p][c] -
__global__ __launch_bounds__(256) void k_gemm_proj(const u16* __restrict__ Wb,
                                                   const u16* __restrict__ aT,
                                                   float* __restrict__ out) {
  int oT = blockIdx.x * 128, pT = blockIdx.y * 128, b = blockIdx.z;
  __shared__ u16 As[128 * 32];
  __shared__ u16 Bs[128 * 32];
  int t = threadIdx.x, lane = t & 63, wid = t >> 6;
  int ln = lane & 15, quad = lane >> 4;
  int wr = wid >> 1, wc = wid & 1;
  v4f acc[4][4] = {};

  int lr = lane >> 2, lc = (lane & 3) * 8;
  const u16* Ag = Wb + (size_t)(oT + wid * 16 + lr) * CDIM + lc;
  const u16* Bg = aT + ((size_t)b * NSEQ + pT + wid * 16 + lr) * CDIM + lc;
  u16* Asl = &As[(wid * 16) * 32];
  u16* Asl2 = &As[(wid * 16 + 64) * 32];
  u16* Bsl = &Bs[(wid * 16) * 32];
  u16* Bsl2 = &Bs[(wid * 16 + 64) * 32];

  for (int kk = 0; kk < CDIM; kk += 32) {
    gload16(Ag + kk, Asl);
    gload16(Ag + (size_t)64 * CDIM + kk, Asl2);
    gload16(Bg + kk, Bsl);
    gload16(Bg + (size_t)64 * CDIM + kk, Bsl2);
    __syncthreads();
    bf16x8 af[4], bfr[4];
#pragma unroll
    for (int mt = 0; mt < 4; ++mt)
      af[mt] = *(const bf16x8*)&As[(wr * 64 + mt * 16 + ln) * 32 + quad * 8];
#pragma unroll
    for (int nt = 0; nt < 4; ++nt)
      bfr[nt] = *(const bf16x8*)&Bs[(wc * 64 + nt * 16 + ln) * 32 + quad * 8];
#pragma unroll
    for (int mt = 0; mt < 4; ++mt)
#pragma unroll
      for (int nt = 0; nt < 4; ++nt)
        acc[mt][nt] = mfma16(af[mt], bfr[nt], acc[mt][nt]);
    __syncthreads();
  }

#pragma unroll
  for (int mt = 0; mt < 4; ++mt) {
#pragma unroll
    for (int nt = 0; nt < 4; ++nt) {
      int ro = oT + wr * 64 + mt * 16 + quad * 4;
      int cp = pT + wc * 64 + nt * 16 + ln;
#pragma unroll
      for (int r = 0; r < 4; ++r)
        out[((size_t)b * CDIM + ro + r) * NSEQ + cp] = acc[mt][nt][r];
    }
  }
}

extern "C" void kernel_launch(void* const* d_in, const int* in_sizes, int n_in,
                              void* d_out, int out_size, void* d_ws, size_t ws_size,
                              hipStream_t stream) {
  const float* x = (const float*)d_in[0];
  const float* w_qkv = (const float*)d_in[1];
  const float* w_proj = (const float*)d_in[2];
  float* out = (float*)d_out;

  char* ws = (char*)d_ws;
  // ws layout (bytes):
  //   wqkv_bf : 2304*768*2       = 3,538,944
  //   wproj_bf: 768*768*2        = 1,179,648
  //   xT      : 8*1024*768*2     = 12,582,912   (reused as attnT after GEMM1)
  //   vbuf    : 8*768*1024*2     = 12,582,912
  // qkT (8*1024*1536*2 = 25,165,824 B) aliases d_out (8*768*1024*4 = same size);
  // qkT is dead before k_gemm_proj writes d_out.
  u16* wqkv_bf = (u16*)(ws);
  u16* wproj_bf = (u16*)(ws + 3538944);
  u16* xT = (u16*)(ws + 4718592);
  u16* vbuf = (u16*)(ws + 17301504);
  u16* qkT = (u16*)d_out;
  u16* attnT = xT;

  k_conv<<<dim3(1728), dim3(256), 0, stream>>>(w_qkv, wqkv_bf, 442368);
  k_conv<<<dim3(576), dim3(256), 0, stream>>>(w_proj, wproj_bf, 147456);
  k_transpose<<<dim3(16, 12, 8), dim3(256), 0, stream>>>(x, xT);
  k_gemm_qkv<<<dim3(9, 8, 8), dim3(512), 0, stream>>>(wqkv_bf, xT, qkT, vbuf);
  k_attn<<<dim3(384), dim3(512), 0, stream>>>(qkT, vbuf, attnT);
  k_gemm_proj<<<dim3(6, 8, 8), dim3(256), 0, stream>>>(wproj_bf, attnT, out);
}

// Round 6
// 206.609 us; speedup vs baseline: 1.0478x; 1.0478x over previous
//
#include <hip/hip_runtime.h>

typedef unsigned short u16;
typedef unsigned int u32;
typedef float v4f __attribute__((ext_vector_type(4)));
typedef __bf16 bf16x8 __attribute__((ext_vector_type(8)));

// Problem constants: x (8, 768, 32x32), w_qkv (2304, 768), w_proj (768, 768)
#define BATCH 8
#define CDIM 768
#define NHEAD 12
#define DH 64
#define NSEQ 1024
// softmax scale folded with log2(e): logits * dh^-0.5 * log2e
#define SCL 0.18033688011112042f

// s_waitcnt immediates (gfx9 encoding): lgkmcnt=15 (no wait), expcnt=7 (no wait)
#define WAIT_VM4 0xF74   // vmcnt(4)
#define WAIT_VM0 0xF70   // vmcnt(0)

__device__ __forceinline__ u16 f2bf(float f) {
  u32 u = __builtin_bit_cast(u32, f);
  u += 0x7fffu + ((u >> 16) & 1u);   // RNE
  return (u16)(u >> 16);
}

__device__ __forceinline__ v4f mfma16(bf16x8 a, bf16x8 b, v4f c) {
  return __builtin_amdgcn_mfma_f32_16x16x32_bf16(a, b, c, 0, 0, 0);
}

// async global->LDS DMA, 16B per lane; LDS dest = wave-uniform base + lane*16
__device__ __forceinline__ void gload16(const u16* g, u16* l) {
  __builtin_amdgcn_global_load_lds(
      (const __attribute__((address_space(1))) void*)g,
      (__attribute__((address_space(3))) void*)l, 16, 0, 0);
}

// ------------- kernel: fused prep --------------------------------------
// blocks [0,1728): w_qkv fp32->bf16 ; [1728,2304): w_proj ; [2304,3840):
// x (b,c,p) -> xT (b,p,c) bf16 transpose. One launch instead of three.
__global__ __launch_bounds__(256) void k_prep(const float* __restrict__ x,
                                              const float* __restrict__ wq,
                                              const float* __restrict__ wp,
                                              u16* __restrict__ xT,
                                              u16* __restrict__ wqb,
                                              u16* __restrict__ wpb) {
  __shared__ u16 Ts[64][72];   // transpose staging; pitch 72 keeps 16B align
  int bid = blockIdx.x;
  int t = threadIdx.x;
  if (bid < 2304) {
    bool isQ = bid < 1728;
    const float* s = isQ ? wq : wp;
    u16* d = isQ ? wqb : wpb;
    int i = (isQ ? bid : bid - 1728) * 256 + t;   // exact coverage, no bounds
    float4 v = ((const float4*)s)[i];
    u32 lo = (u32)f2bf(v.x) | ((u32)f2bf(v.y) << 16);
    u32 hi = (u32)f2bf(v.z) | ((u32)f2bf(v.w) << 16);
    ((uint2*)d)[i] = uint2{lo, hi};
    return;
  }
  int id = bid - 2304;
  int p0 = (id & 15) * 64; id >>= 4;
  int c0 = (id % 12) * 64; int b = id / 12;
  int cr = t >> 4;             // 0..15
  int p4 = (t & 15) * 4;       // 0..60
  const float* src = x + ((size_t)b * CDIM + c0) * NSEQ + p0;
#pragma unroll
  for (int i = 0; i < 4; ++i) {
    int c = cr + i * 16;
    float4 v = *(const float4*)&src[(size_t)c * NSEQ + p4];
    Ts[p4 + 0][c] = f2bf(v.x);
    Ts[p4 + 1][c] = f2bf(v.y);
    Ts[p4 + 2][c] = f2bf(v.z);
    Ts[p4 + 3][c] = f2bf(v.w);
  }
  __syncthreads();
  int p = t >> 2;              // 0..63
  int cq = t & 3;
  u16* dst = xT + ((size_t)b * NSEQ + p0 + p) * CDIM + c0;
#pragma unroll
  for (int j = 0; j < 2; ++j) {
    int ch = cq + j * 4;       // 8 chunks of 8 bf16 = 64 elems
    *(int4*)&dst[ch * 8] = *(const int4*)&Ts[p][ch * 8];
  }
}

// ------------- kernel: QKV GEMM  D[o][p] = sum_c W[o][c] * xT[p][c] -----
// 128x128 tile, 256 thr, BK=32, EXPLICIT LDS DOUBLE-BUFFER:
// tile k+1's 4 DMAs issue into the alternate buffer BEFORE waiting for
// tile k; raw s_waitcnt vmcnt(4) waits only the 4 oldest (tile k) loads;
// raw s_barrier avoids the compiler's vmcnt(0) drain at __syncthreads.
// Q,K rows (o<1536) stored transposed qkT[b][p][o]; V rows to vbuf[b][d][p].
__global__ __launch_bounds__(256) void k_gemm_qkv(const u16* __restrict__ Wb,
                                                  const u16* __restrict__ xT,
                                                  u16* __restrict__ qkT,
                                                  u16* __restrict__ vbuf) {
  int oT = blockIdx.x * 128, pT = blockIdx.y * 128, b = blockIdx.z;
  __shared__ u16 As[2][128 * 32];   // 16 KB
  __shared__ u16 Bs[2][128 * 32];   // 16 KB
  int t = threadIdx.x, lane = t & 63, wid = t >> 6;
  int ln = lane & 15, quad = lane >> 4;
  int wr = wid >> 1, wc = wid & 1;
  v4f acc[4][4] = {};

  // DMA staging: wave wid covers 16-row slabs at wid*16 and wid*16+64.
  int lr = lane >> 2, lc = (lane & 3) * 8;
  const u16* Ag = Wb + (size_t)(oT + wid * 16 + lr) * CDIM + lc;
  const u16* Bg = xT + ((size_t)b * NSEQ + pT + wid * 16 + lr) * CDIM + lc;
  int s0 = (wid * 16) * 32, s1 = (wid * 16 + 64) * 32;

  // prologue: tile 0 -> buf 0
  gload16(Ag, &As[0][s0]);
  gload16(Ag + (size_t)64 * CDIM, &As[0][s1]);
  gload16(Bg, &Bs[0][s0]);
  gload16(Bg + (size_t)64 * CDIM, &Bs[0][s1]);

#pragma unroll 2
  for (int k = 0; k < 24; ++k) {
    int cur = k & 1, nxt = cur ^ 1;
    if (k < 23) {
      int kk = (k + 1) * 32;
      gload16(Ag + kk, &As[nxt][s0]);
      gload16(Ag + (size_t)64 * CDIM + kk, &As[nxt][s1]);
      gload16(Bg + kk, &Bs[nxt][s0]);
      gload16(Bg + (size_t)64 * CDIM + kk, &Bs[nxt][s1]);
      __builtin_amdgcn_s_waitcnt(WAIT_VM4);   // tile k's 4 loads done
    } else {
      __builtin_amdgcn_s_waitcnt(WAIT_VM0);
    }
    __builtin_amdgcn_s_barrier();             // all waves' tile-k data in LDS
    bf16x8 af[4], bfr[4];
#pragma unroll
    for (int mt = 0; mt < 4; ++mt)
      af[mt] = *(const bf16x8*)&As[cur][(wr * 64 + mt * 16 + ln) * 32 + quad * 8];
#pragma unroll
    for (int nt = 0; nt < 4; ++nt)
      bfr[nt] = *(const bf16x8*)&Bs[cur][(wc * 64 + nt * 16 + ln) * 32 + quad * 8];
#pragma unroll
    for (int mt = 0; mt < 4; ++mt)
#pragma unroll
      for (int nt = 0; nt < 4; ++nt)
        acc[mt][nt] = mfma16(af[mt], bfr[nt], acc[mt][nt]);
    __builtin_amdgcn_s_barrier();             // release buf[cur] for k+2's DMA
  }

  bool isV = (oT >= 2 * CDIM);
#pragma unroll
  for (int mt = 0; mt < 4; ++mt) {
#pragma unroll
    for (int nt = 0; nt < 4; ++nt) {
      int ro = oT + wr * 64 + mt * 16 + quad * 4;   // 4 consecutive o rows
      int cp = pT + wc * 64 + nt * 16 + ln;
      if (!isV) {
        u32 lo = (u32)f2bf(acc[mt][nt][0]) | ((u32)f2bf(acc[mt][nt][1]) << 16);
        u32 hi = (u32)f2bf(acc[mt][nt][2]) | ((u32)f2bf(acc[mt][nt][3]) << 16);
        *(uint2*)&qkT[((size_t)b * NSEQ + cp) * 1536 + ro] = uint2{lo, hi};
      } else {
#pragma unroll
        for (int r = 0; r < 4; ++r)
          vbuf[((size_t)b * CDIM + (ro - 2 * CDIM + r)) * NSEQ + cp] =
              f2bf(acc[mt][nt][r]);
      }
    }
  }
}

// ------------- kernel: flash attention (v3) -----------------------------
// 512 threads = 8 waves; block owns 256 query rows of one (b,h).
// 1-D grid decoded so flat_id%8 = b (XCD affinity): one batch's whole K+V
// (3.1 MB) stays in that XCD's L2; the 4 n-tile blocks per (b,h) are
// dispatch-adjacent so they stream K/V from L2, not HBM.
// S^T = K·Q^T (P exits in packed-per-lane m-order -> b64 LDS stores in
// A-layout); no-max softmax (logits N(0,~1.4) after scale), one final sum.
__global__ __launch_bounds__(512) void k_attn(const u16* __restrict__ qkT,
                                              const u16* __restrict__ vbuf,
                                              u16* __restrict__ attnT) {
  int id = blockIdx.x;
  int b = id & 7;              // XCD slot under flat%8 round-robin
  int j = id >> 3;
  int ntile = j & 3;
  int h = j >> 2;              // 0..11
  int nt0 = ntile * 256;

  int t = threadIdx.x, lane = t & 63, wid = t >> 6;
  int ln = lane & 15, quad = lane >> 4;
  int nbase = nt0 + wid * 32;

  __shared__ u16 Ks[64 * 72];      // [key m][dh k], pitch 72
  __shared__ u16 Vs[64 * 72];      // [d][key m], pitch 72
  __shared__ u16 Pa[8][32 * 72];   // per wave: [n_local][m_local], pitch 72
  u16* myP = Pa[wid];

  // Q frags (B operand of S^T): B[col=n][k], lane ln = n_local & 15
  const u16* qbase = qkT + ((size_t)b * NSEQ + nbase) * 1536 + h * DH;
  bf16x8 aq[2][2];
#pragma unroll
  for (int mt = 0; mt < 2; ++mt)
#pragma unroll
    for (int ks = 0; ks < 2; ++ks)
      aq[mt][ks] = *(const bf16x8*)&qbase[(size_t)(mt * 16 + ln) * 1536 + ks * 32 + quad * 8];

  v4f oacc[2][4] = {};
  float lsum[2] = {0.0f, 0.0f};

  const u16* kg0 = qkT + (size_t)b * NSEQ * 1536 + CDIM + h * DH;
  const u16* vg0 = vbuf + ((size_t)b * CDIM + h * DH) * NSEQ;
  int sr = t >> 3;              // 0..63 staging row (512 threads)
  int sc = (t & 7) * 8;         // 16B chunk within 64-elem row

  for (int m0 = 0; m0 < NSEQ; m0 += 64) {
    __syncthreads();            // all waves done reading prev Ks/Vs
    *(int4*)&Ks[sr * 72 + sc] = *(const int4*)(kg0 + (size_t)(m0 + sr) * 1536 + sc);
    *(int4*)&Vs[sr * 72 + sc] = *(const int4*)(vg0 + (size_t)sr * NSEQ + m0 + sc);
    __syncthreads();

    // S^T tiles: rows = keys (ct), cols = queries (mt); p = exp2(s*SCL)
#pragma unroll
    for (int ct = 0; ct < 4; ++ct) {
      bf16x8 kf0 = *(const bf16x8*)&Ks[(ct * 16 + ln) * 72 + quad * 8];
      bf16x8 kf1 = *(const bf16x8*)&Ks[(ct * 16 + ln) * 72 + 32 + quad * 8];
#pragma unroll
      for (int mt = 0; mt < 2; ++mt) {
        v4f s = {};
        s = mfma16(kf0, aq[mt][0], s);
        s = mfma16(kf1, aq[mt][1], s);
        float p0 = __builtin_amdgcn_exp2f(s[0] * SCL);
        float p1 = __builtin_amdgcn_exp2f(s[1] * SCL);
        float p2 = __builtin_amdgcn_exp2f(s[2] * SCL);
        float p3 = __builtin_amdgcn_exp2f(s[3] * SCL);
        lsum[mt] += (p0 + p1) + (p2 + p3);
        u32 lo = (u32)f2bf(p0) | ((u32)f2bf(p1) << 16);
        u32 hi = (u32)f2bf(p2) | ((u32)f2bf(p3) << 16);
        // lane holds P[n=mt*16+ln][m=ct*16+quad*4 .. +3] -> one 8B store
        *(uint2*)&myP[(mt * 16 + ln) * 72 + ct * 16 + quad * 4] = uint2{lo, hi};
      }
    }

    // PV: A = P (row=n, k=m), B = V (col=d, k=m)
    bf16x8 ap[2][2];
#pragma unroll
    for (int mt = 0; mt < 2; ++mt)
#pragma unroll
      for (int ks = 0; ks < 2; ++ks)
        ap[mt][ks] = *(const bf16x8*)&myP[(mt * 16 + ln) * 72 + ks * 32 + quad * 8];
#pragma unroll
    for (int nt = 0; nt < 4; ++nt) {
      bf16x8 vf0 = *(const bf16x8*)&Vs[(nt * 16 + ln) * 72 + quad * 8];
      bf16x8 vf1 = *(const bf16x8*)&Vs[(nt * 16 + ln) * 72 + 32 + quad * 8];
#pragma unroll
      for (int mt = 0; mt < 2; ++mt) {
        oacc[mt][nt] = mfma16(ap[mt][0], vf0, oacc[mt][nt]);
        oacc[mt][nt] = mfma16(ap[mt][1], vf1, oacc[mt][nt]);
      }
    }
  }

  // lsum[mt] per lane covers this quad's m-slices for n = mt*16+ln;
  // reduce across the 4 quad groups (lanes ln, ln+16, ln+32, ln+48).
#pragma unroll
  for (int mt = 0; mt < 2; ++mt) {
    lsum[mt] += __shfl_xor(lsum[mt], 16);
    lsum[mt] += __shfl_xor(lsum[mt], 32);
  }

  // normalize and store O as attnT[b][n][c]; O C-layout row = quad*4+r
#pragma unroll
  for (int mt = 0; mt < 2; ++mt) {
#pragma unroll
    for (int r = 0; r < 4; ++r) {
      float l = __shfl(lsum[mt], quad * 4 + r, 16);   // holder lane ln = quad*4+r
      float inv = 1.0f / l;
      int n = nbase + mt * 16 + quad * 4 + r;
      u16* dst = attnT + ((size_t)b * NSEQ + n) * CDIM + h * DH;
#pragma unroll
      for (int nt = 0; nt < 4; ++nt)
        dst[nt * 16 + ln] = f2bf(oacc[mt][nt][r] * inv);
    }
  }
}

// ------------- kernel: proj GEMM  out[o][p] = sum_c Wp[o][c]*attnT[p][c] -
// Grid (b, oT, pT) b-fastest: per-batch working set (aT 1.6MB + W 1.2MB)
// fits one XCD's 4MB L2 -> b-fastest was ~16us faster (round-4 vs round-5).
__global__ __launch_bounds__(256) void k_gemm_proj(const u16* __restrict__ Wb,
                                                   const u16* __restrict__ aT,
                                                   float* __restrict__ out) {
  int b = blockIdx.x, oT = blockIdx.y * 128, pT = blockIdx.z * 128;
  __shared__ u16 As[128 * 32];
  __shared__ u16 Bs[128 * 32];
  int t = threadIdx.x, lane = t & 63, wid = t >> 6;
  int ln = lane & 15, quad = lane >> 4;
  int wr = wid >> 1, wc = wid & 1;
  v4f acc[4][4] = {};

  int lr = lane >> 2, lc = (lane & 3) * 8;
  const u16* Ag = Wb + (size_t)(oT + wid * 16 + lr) * CDIM + lc;
  const u16* Bg = aT + ((size_t)b * NSEQ + pT + wid * 16 + lr) * CDIM + lc;
  u16* Asl = &As[(wid * 16) * 32];
  u16* Asl2 = &As[(wid * 16 + 64) * 32];
  u16* Bsl = &Bs[(wid * 16) * 32];
  u16* Bsl2 = &Bs[(wid * 16 + 64) * 32];

  for (int kk = 0; kk < CDIM; kk += 32) {
    gload16(Ag + kk, Asl);
    gload16(Ag + (size_t)64 * CDIM + kk, Asl2);
    gload16(Bg + kk, Bsl);
    gload16(Bg + (size_t)64 * CDIM + kk, Bsl2);
    __syncthreads();
    bf16x8 af[4], bfr[4];
#pragma unroll
    for (int mt = 0; mt < 4; ++mt)
      af[mt] = *(const bf16x8*)&As[(wr * 64 + mt * 16 + ln) * 32 + quad * 8];
#pragma unroll
    for (int nt = 0; nt < 4; ++nt)
      bfr[nt] = *(const bf16x8*)&Bs[(wc * 64 + nt * 16 + ln) * 32 + quad * 8];
#pragma unroll
    for (int mt = 0; mt < 4; ++mt)
#pragma unroll
      for (int nt = 0; nt < 4; ++nt)
        acc[mt][nt] = mfma16(af[mt], bfr[nt], acc[mt][nt]);
    __syncthreads();
  }

#pragma unroll
  for (int mt = 0; mt < 4; ++mt) {
#pragma unroll
    for (int nt = 0; nt < 4; ++nt) {
      int ro = oT + wr * 64 + mt * 16 + quad * 4;
      int cp = pT + wc * 64 + nt * 16 + ln;
#pragma unroll
      for (int r = 0; r < 4; ++r)
        out[((size_t)b * CDIM + ro + r) * NSEQ + cp] = acc[mt][nt][r];
    }
  }
}

extern "C" void kernel_launch(void* const* d_in, const int* in_sizes, int n_in,
                              void* d_out, int out_size, void* d_ws, size_t ws_size,
                              hipStream_t stream) {
  const float* x = (const float*)d_in[0];
  const float* w_qkv = (const float*)d_in[1];
  const float* w_proj = (const float*)d_in[2];
  float* out = (float*)d_out;

  char* ws = (char*)d_ws;
  // ws layout (bytes):
  //   wqkv_bf : 2304*768*2       = 3,538,944
  //   wproj_bf: 768*768*2        = 1,179,648
  //   xT      : 8*1024*768*2     = 12,582,912   (reused as attnT after GEMM1)
  //   vbuf    : 8*768*1024*2     = 12,582,912
  // qkT (8*1024*1536*2 = 25,165,824 B) aliases d_out (8*768*1024*4 = same size);
  // qkT is dead before k_gemm_proj writes d_out.
  u16* wqkv_bf = (u16*)(ws);
  u16* wproj_bf = (u16*)(ws + 3538944);
  u16* xT = (u16*)(ws + 4718592);
  u16* vbuf = (u16*)(ws + 17301504);
  u16* qkT = (u16*)d_out;
  u16* attnT = xT;

  k_prep<<<dim3(3840), dim3(256), 0, stream>>>(x, w_qkv, w_proj, xT, wqkv_bf, wproj_bf);
  k_gemm_qkv<<<dim3(18, 8, 8), dim3(256), 0, stream>>>(wqkv_bf, xT, qkT, vbuf);
  k_attn<<<dim3(384), dim3(512), 0, stream>>>(qkT, vbuf, attnT);
  k_gemm_proj<<<dim3(8, 6, 8), dim3(256), 0, stream>>>(wproj_bf, attnT, out);
}